// Round 10
// baseline (238.713 us; speedup 1.0000x reference)
//
#include <hip/hip_runtime.h>

// GCN: h' = relu(A @ (h @ W) + b) x3, last layer no relu.
// Round 22: r21 fused pipeline + tighter pre-chain schedule.
// r21 proved concurrency is the remaining lever (-6.6us from part||gemm0).
// Dependencies allow: memset(bfill,sentinel) -> [prep || part] ->
// [sort || gemm0] -> fused chain. Saves ~6us of serial pre-chain + 1 gap.
//  - k_pp: blocks 0..223 = weight transpose (2 rows/block), 224..419 = part.
//  - k_sg: blocks 0..390 = within-bucket sort, 391..1172 = gemm0 (MFMA);
//    LDS union (sort's 1.6KB aliases gemm0's 34.8KB sWt).
// Agg/GEMM chain identical to r21/r20 (group-per-node, 8 edges/step,
// zeroed-sentinel clamp; transaction-rate-pinned ~40us/pass, proven
// invariant to depth/layout/regs/fusion across r15-r20).

constexpr int NN = 50000;          // nodes
constexpr int NE = 800000;         // edges
constexpr int NB = (NN + 127) >> 7;          // 391 buckets (dst >> 7)
constexpr int CAP = 4608;                    // padded bucket capacity
constexpr int PART_CHUNK = 4096;             // edges per partition block
constexpr int PART_GRID = (NE + PART_CHUNK - 1) / PART_CHUNK;  // 196
constexpr int ZOFF = NB * CAP;               // 16 zeroed sentinel slots
constexpr int PREP_GRID = 224;               // 448 weight rows / 2

typedef __attribute__((ext_vector_type(8))) short bf16x8;
typedef __attribute__((ext_vector_type(4))) float floatx4;
typedef __attribute__((ext_vector_type(2))) float floatx2;
typedef __attribute__((ext_vector_type(4))) unsigned int uintx4;

__device__ inline unsigned short f2bf(float f) {          // RNE fp32->bf16
    unsigned u = __float_as_uint(f);
    u += 0x7fffu + ((u >> 16) & 1u);
    return (unsigned short)(u >> 16);
}
__device__ inline float bflo(unsigned v) { return __uint_as_float(v << 16); }
__device__ inline float bfhi(unsigned v) { return __uint_as_float(v & 0xffff0000u); }
__device__ inline unsigned char f2fp8(float f) {          // fp32 -> e4m3 (HW)
    return (unsigned char)(__builtin_amdgcn_cvt_pk_fp8_f32(f, f, 0, false) & 0xff);
}

// ---------------- merged: weight transpose (0..223) || part (224..419) -----

__global__ __launch_bounds__(256) void k_pp(
        const float* __restrict__ W0, const float* __restrict__ W1,
        const float* __restrict__ W2, const float* __restrict__ W3,
        unsigned short* __restrict__ T0, unsigned short* __restrict__ T1,
        unsigned short* __restrict__ T2, unsigned short* __restrict__ T3,
        const int* __restrict__ src, const int* __restrict__ dst,
        const float* __restrict__ w, int* __restrict__ bfill,
        int2* __restrict__ ep) {
    const int tid = threadIdx.x;

    if (blockIdx.x < PREP_GRID) {
        // ---- prep role: rows 2b, 2b+1 of the flattened 448-row space ----
        int r = blockIdx.x * 2 + (tid >> 7);     // 0..447
        int k = tid & 127;
        const float* W; unsigned short* T; int N, n;
        if (r < 128)      { W = W0; T = T0; N = 128; n = r; }
        else if (r < 256) { W = W1; T = T1; N = 128; n = r - 128; }
        else if (r < 384) { W = W2; T = T2; N = 128; n = r - 256; }
        else              { W = W3; T = T3; N = 64;  n = r - 384; }
        T[n * 128 + k] = f2bf(W[(size_t)k * N + n]);
        return;
    }

    // ---- part role ----
    __shared__ int hist[NB], base[NB], off[NB];
    for (int b = tid; b < NB; b += 256) { hist[b] = 0; off[b] = 0; }
    __syncthreads();

    int e0 = (blockIdx.x - PREP_GRID) * PART_CHUNK;
    int  sreg[16]; int wreg[16]; short breg[16];
#pragma unroll
    for (int i = 0; i < 16; ++i) {
        int e = e0 + i * 256 + tid;
        if (e < NE) {
            int d = dst[e];
            int b = d >> 7;
            sreg[i] = (src[e] & 0xffff) | ((d & 127) << 16);
            wreg[i] = __float_as_int(w[e]);
            breg[i] = (short)b;
            atomicAdd(&hist[b], 1);
        } else breg[i] = -1;
    }
    __syncthreads();
    for (int b = tid; b < NB; b += 256)
        base[b] = b * CAP + atomicAdd(&bfill[b], hist[b]);
    __syncthreads();
#pragma unroll
    for (int i = 0; i < 16; ++i) {
        if (breg[i] >= 0) {
            int b = breg[i];
            int p = atomicAdd(&off[b], 1);
            ep[base[b] + p] = make_int2(sreg[i], wreg[i]);
        }
    }
}

// ---------------- merged: sort (0..390) || gemm0 (391..1172) ---------------

__device__ inline bf16x8 ldA_f32(const float* A, size_t off) {
    float4 u = *(const float4*)&A[off];
    float4 v = *(const float4*)&A[off + 4];
    bf16x8 r;
    r[0] = (short)f2bf(u.x); r[1] = (short)f2bf(u.y);
    r[2] = (short)f2bf(u.z); r[3] = (short)f2bf(u.w);
    r[4] = (short)f2bf(v.x); r[5] = (short)f2bf(v.y);
    r[6] = (short)f2bf(v.z); r[7] = (short)f2bf(v.w);
    return r;
}

__global__ __launch_bounds__(256) void k_sg(
        const int2* __restrict__ ep, const int* __restrict__ bfill,
        unsigned* __restrict__ es, int2* __restrict__ begend,
        const float* __restrict__ A,            // x [M][128] fp32
        const unsigned short* __restrict__ Wt,  // Wt0 [128][128] bf16
        unsigned char* __restrict__ C,          // sup [M][128] fp8
        int M) {
    constexpr int STR = 136;
    __shared__ int smem[128 * STR / 2];         // 34816 B, shared by roles
    const int tid = threadIdx.x;

    if (blockIdx.x < NB) {
        // ---- sort role (within-bucket dst sort, pad-16) ----
        int* cnt  = smem;            // [128]
        int* base = smem + 128;      // [128]
        int* fl   = smem + 256;      // [128]
        int* stot = smem + 384;      // [1]
        int b  = blockIdx.x;
        int n0 = b << 7;
        int nn = min(128, NN - n0);
        int t  = tid;
        if (t < 128) { cnt[t] = 0; fl[t] = 0; }
        __syncthreads();
        int bbase = b * CAP;
        int beg = bbase, end = bbase + bfill[b];
        for (int e = beg + t; e < end; e += 256)
            atomicAdd(&cnt[(ep[e].x >> 16) & 127], 1);
        __syncthreads();
        int cp = (t < 128) ? ((cnt[t] + 15) & ~15) : 0;
        if (t < 128) base[t] = cp;
        __syncthreads();
        for (int off = 1; off < 128; off <<= 1) {
            int add = (t >= off && t < 128) ? base[t - off] : 0;
            __syncthreads();
            if (t < 128) base[t] += add;     // inclusive scan of padded counts
            __syncthreads();
        }
        if (t == 127) *stot = base[127];
        __syncthreads();
        int total = *stot;
        for (int i = t; i < total + 16; i += 256) es[bbase + i] = 0u;
        if (t < nn) {
            int off = base[t] - cp;
            begend[n0 + t] = make_int2(bbase + off, bbase + off + cp);
        }
        __syncthreads();
        for (int e = beg + t; e < end; e += 256) {
            int2 v = ep[e];
            int d = (v.x >> 16) & 127;
            int off = base[d] - ((cnt[d] + 15) & ~15);
            int pos = bbase + off + atomicAdd(&fl[d], 1);
            es[pos] = (unsigned)(v.x & 0xffff) |
                      ((unsigned)f2bf(__int_as_float(v.y)) << 16);
        }
        return;
    }

    // ---- gemm0 role ----
    unsigned short* sWt = (unsigned short*)smem;
    const int gb = blockIdx.x - NB;
#pragma unroll
    for (int i = 0; i < 8; ++i) {
        int c = i * 256 + tid;
        int row = c >> 4, col = (c & 15) * 8;
        *(uint4*)&sWt[row * STR + col] = *(const uint4*)&Wt[row * 128 + col];
    }

    const int wv = tid >> 6;
    const int ln = tid & 63;
    const int m  = ln & 15;
    const int qd = ln >> 4;

    int gr  = gb * 64 + wv * 16 + m;
    int grc = (gr < M) ? gr : (M - 1);
    bf16x8 af[4];
#pragma unroll
    for (int s = 0; s < 4; ++s)
        af[s] = ldA_f32(A, (size_t)grc * 128 + s * 32 + qd * 8);

    __syncthreads();

    floatx4 acc[8];
#pragma unroll
    for (int c = 0; c < 8; ++c) {
        acc[c] = (floatx4){0.f, 0.f, 0.f, 0.f};
#pragma unroll
        for (int s = 0; s < 4; ++s) {
            bf16x8 bf = *(const bf16x8*)&sWt[(c * 16 + m) * STR + s * 32 + qd * 8];
            acc[c] = __builtin_amdgcn_mfma_f32_16x16x32_bf16(af[s], bf, acc[c], 0, 0, 0);
        }
    }

    int row0 = gb * 64 + wv * 16 + qd * 4;
#pragma unroll
    for (int c = 0; c < 8; ++c)
#pragma unroll
        for (int r = 0; r < 4; ++r) {
            int row = row0 + r;
            if (row < M) C[(size_t)row * 128 + c * 16 + m] = f2fp8(acc[c][r]);
        }
}

// ---------------- Fused agg(layer i) + GEMM(layer i+1) ---------------------
// Agg phase: 16 groups x 16 lanes; group owns one node; lane l owns cols
// l*8..l*8+7 of the 128-col fp8 row (uint2 gather; 16 lanes = 128B = one
// L2 line). 8 edges/step, meta software-pipelined, sentinel clamp, all
// in-register (no shuffles). relu+bias -> bf16 tile in LDS.
// GEMM phase: 4 waves; wave wv computes col-tiles c0..c0+NT/4-1 with
// B-fragments straight from L2-hot Wt. Output row-major fp8 or bf16.

#define FMAP8(W, R)                                                             \
    { floatx2 p0 = __builtin_amdgcn_cvt_pk_f32_fp8((int)(R).x, false);          \
      floatx2 p1 = __builtin_amdgcn_cvt_pk_f32_fp8((int)(R).x, true);           \
      floatx2 p2 = __builtin_amdgcn_cvt_pk_f32_fp8((int)(R).y, false);          \
      floatx2 p3 = __builtin_amdgcn_cvt_pk_f32_fp8((int)(R).y, true);           \
      acc[0] = fmaf(W, p0.x, acc[0]); acc[1] = fmaf(W, p0.y, acc[1]);           \
      acc[2] = fmaf(W, p1.x, acc[2]); acc[3] = fmaf(W, p1.y, acc[3]);           \
      acc[4] = fmaf(W, p2.x, acc[4]); acc[5] = fmaf(W, p2.y, acc[5]);           \
      acc[6] = fmaf(W, p3.x, acc[6]); acc[7] = fmaf(W, p3.y, acc[7]); }

#define GATHF(R, MV)                                                            \
    uint2 R = *(const uint2*)&sup[(size_t)((MV) & 0xffffu) * 128 + l * 8];

template<int NOUT, typename CT>
__global__ __launch_bounds__(256) void k_fused(
        const unsigned char* __restrict__ sup,   // [NN][128] fp8
        const int2* __restrict__ begend, const unsigned* __restrict__ es,
        const float* __restrict__ bias,          // layer-i bias (relu applied)
        const unsigned short* __restrict__ Wt,   // [NOUT][128] bf16
        CT* __restrict__ C,                      // [M][NOUT] fp8 or bf16
        int M) {
    constexpr int NT  = NOUT / 16;
    constexpr int STR = 136;
    __shared__ unsigned short hT[16 * STR];

    const int tid = threadIdx.x;
    const int l   = tid & 15;                    // col slot (8 fp8 each)
    const int n0  = blockIdx.x * 16;
    const int n   = n0 + (tid >> 4);             // group's node
    const bool nv = n < NN;

    int2 be = nv ? begend[n] : make_int2(0, 0);
    const int en = be.y;
    int e = be.x;
    float acc[8] = {0.f, 0.f, 0.f, 0.f, 0.f, 0.f, 0.f, 0.f};
    bool v = e < en;
    if (__any(v)) {
        int ei = v ? e : ZOFF;
        uintx4 m0 = __builtin_nontemporal_load((const uintx4*)&es[ei]);
        uintx4 m1 = __builtin_nontemporal_load((const uintx4*)&es[ei + 4]);
        for (;;) {
            GATHF(r0, m0[0]); GATHF(r1, m0[1]); GATHF(r2, m0[2]); GATHF(r3, m0[3]);
            GATHF(r4, m1[0]); GATHF(r5, m1[1]); GATHF(r6, m1[2]); GATHF(r7, m1[3]);
            float w0 = bfhi(m0[0]), w1 = bfhi(m0[1]), w2 = bfhi(m0[2]), w3 = bfhi(m0[3]);
            float w4 = bfhi(m1[0]), w5 = bfhi(m1[1]), w6 = bfhi(m1[2]), w7 = bfhi(m1[3]);
            e += 8;
            v = e < en;
            bool more = __any(v);
            int eo = v ? e : ZOFF;               // clamp to zeroed sentinel
            uintx4 p0 = __builtin_nontemporal_load((const uintx4*)&es[eo]);
            uintx4 p1 = __builtin_nontemporal_load((const uintx4*)&es[eo + 4]);
            FMAP8(w0, r0); FMAP8(w1, r1); FMAP8(w2, r2); FMAP8(w3, r3);
            FMAP8(w4, r4); FMAP8(w5, r5); FMAP8(w6, r6); FMAP8(w7, r7);
            m0 = p0; m1 = p1;
            if (!more) break;
        }
    }
    {   // bias + relu -> bf16 LDS tile (every group writes its row slice)
        uintx4 pk;
#pragma unroll
        for (int q = 0; q < 4; ++q) {
            float a0 = fmaxf(acc[2 * q]     + bias[l * 8 + 2 * q],     0.f);
            float a1 = fmaxf(acc[2 * q + 1] + bias[l * 8 + 2 * q + 1], 0.f);
            pk[q] = (unsigned)f2bf(a0) | ((unsigned)f2bf(a1) << 16);
        }
        *(uintx4*)&hT[(tid >> 4) * STR + l * 8] = pk;
    }
    __syncthreads();

    // GEMM phase: 4 waves; wave wv owns NT/4 col-tiles.
    const int wv = tid >> 6;
    const int ln = tid & 63;
    const int m_ = ln & 15, qd = ln >> 4;
    const int c0 = wv * (NT / 4);
    bf16x8 af[4];
#pragma unroll
    for (int s = 0; s < 4; ++s)
        af[s] = *(const bf16x8*)&hT[m_ * STR + s * 32 + qd * 8];

    floatx4 acc2[NT / 4];
#pragma unroll
    for (int c = 0; c < NT / 4; ++c) {
        acc2[c] = (floatx4){0.f, 0.f, 0.f, 0.f};
#pragma unroll
        for (int s = 0; s < 4; ++s) {
            bf16x8 bf = *(const bf16x8*)&Wt[(size_t)((c0 + c) * 16 + m_) * 128 + s * 32 + qd * 8];
            acc2[c] = __builtin_amdgcn_mfma_f32_16x16x32_bf16(af[s], bf, acc2[c], 0, 0, 0);
        }
    }
    int row0 = n0 + qd * 4;
#pragma unroll
    for (int c = 0; c < NT / 4; ++c)
#pragma unroll
        for (int r = 0; r < 4; ++r) {
            int row = row0 + r;
            if (row < M) {
                if constexpr (sizeof(CT) == 1)
                    C[(size_t)row * NOUT + (c0 + c) * 16 + m_] = (CT)f2fp8(acc2[c][r]);
                else
                    C[(size_t)row * NOUT + (c0 + c) * 16 + m_] = (CT)f2bf(acc2[c][r]);
            }
        }
}

// ---------------- Final aggregate (layer 3): out fp32, no relu -------------
// Group-per-node: 16 groups x 16 lanes; lane l owns cols l*4..l*4+3 of the
// bf16 [NN][64] row (uint2 = 8B; 16 lanes = 128B = one line). 8 edges/step.

#define FMA4(W, R)                                                              \
    acc[0] = fmaf(W, bflo((R).x), acc[0]); acc[1] = fmaf(W, bfhi((R).x), acc[1]); \
    acc[2] = fmaf(W, bflo((R).y), acc[2]); acc[3] = fmaf(W, bfhi((R).y), acc[3]);

#define GATHO(R, MV)                                                            \
    uint2 R = *(const uint2*)&sup[(size_t)((MV) & 0xffffu) * 64 + l * 4];

__global__ __launch_bounds__(256) void k_agg64(
        const unsigned short* __restrict__ sup,  // [NN][64] bf16
        const int2* __restrict__ begend, const unsigned* __restrict__ es,
        const float* __restrict__ bias, float* __restrict__ out) {
    const int tid = threadIdx.x;
    const int l   = tid & 15;
    const int n   = blockIdx.x * 16 + (tid >> 4);
    const bool nv = n < NN;

    int2 be = nv ? begend[n] : make_int2(0, 0);
    const int en = be.y;
    int e = be.x;
    float acc[4] = {0.f, 0.f, 0.f, 0.f};
    bool v = e < en;
    if (__any(v)) {
        int ei = v ? e : ZOFF;
        uintx4 m0 = __builtin_nontemporal_load((const uintx4*)&es[ei]);
        uintx4 m1 = __builtin_nontemporal_load((const uintx4*)&es[ei + 4]);
        for (;;) {
            GATHO(r0, m0[0]); GATHO(r1, m0[1]); GATHO(r2, m0[2]); GATHO(r3, m0[3]);
            GATHO(r4, m1[0]); GATHO(r5, m1[1]); GATHO(r6, m1[2]); GATHO(r7, m1[3]);
            float w0 = bfhi(m0[0]), w1 = bfhi(m0[1]), w2 = bfhi(m0[2]), w3 = bfhi(m0[3]);
            float w4 = bfhi(m1[0]), w5 = bfhi(m1[1]), w6 = bfhi(m1[2]), w7 = bfhi(m1[3]);
            e += 8;
            v = e < en;
            bool more = __any(v);
            int eo = v ? e : ZOFF;               // clamp to zeroed sentinel
            uintx4 p0 = __builtin_nontemporal_load((const uintx4*)&es[eo]);
            uintx4 p1 = __builtin_nontemporal_load((const uintx4*)&es[eo + 4]);
            FMA4(w0, r0); FMA4(w1, r1); FMA4(w2, r2); FMA4(w3, r3);
            FMA4(w4, r4); FMA4(w5, r5); FMA4(w6, r6); FMA4(w7, r7);
            m0 = p0; m1 = p1;
            if (!more) break;
        }
    }
    if (nv) {
        float4 o = make_float4(acc[0] + bias[l * 4],     acc[1] + bias[l * 4 + 1],
                               acc[2] + bias[l * 4 + 2], acc[3] + bias[l * 4 + 3]);
        *(float4*)&out[(size_t)n * 64 + l * 4] = o;
    }
}

// ---------------- launch ----------------

extern "C" void kernel_launch(void* const* d_in, const int* in_sizes, int n_in,
                              void* d_out, int out_size, void* d_ws, size_t ws_size,
                              hipStream_t stream) {
    (void)in_sizes; (void)n_in; (void)out_size; (void)ws_size;

    const float* x    = (const float*)d_in[0];
    const int*   esrc = (const int*)d_in[1];
    const int*   edst = (const int*)d_in[2];
    const float* ew   = (const float*)d_in[3];
    const float* W0   = (const float*)d_in[4];
    const float* b0   = (const float*)d_in[5];
    const float* W1   = (const float*)d_in[6];
    const float* b1   = (const float*)d_in[7];
    const float* W2   = (const float*)d_in[8];
    const float* b2   = (const float*)d_in[9];
    const float* W3   = (const float*)d_in[10];
    const float* b3   = (const float*)d_in[11];

    char* p = (char*)d_ws;
    auto alloc = [&](size_t bytes) {
        char* r = p;
        p += (bytes + 511) & ~size_t(511);
        return r;
    };
    int*      bfill  = (int*)     alloc((size_t)NB * 4);
    int2*     begend = (int2*)    alloc((size_t)NN * 8);
    int2*     ep     = (int2*)    alloc((size_t)NB * CAP * 8);
    unsigned* es     = (unsigned*)alloc(((size_t)NB * CAP + 64) * 4);
    unsigned char*  s8a = (unsigned char*) alloc((size_t)NN * 128);    // [NN][128]
    unsigned char*  s8b = (unsigned char*) alloc((size_t)NN * 128);    // [NN][128]
    unsigned short* s16 = (unsigned short*)alloc((size_t)NN * 64 * 2); // [NN][64]
    unsigned short* Wt0 = (unsigned short*)alloc((size_t)128 * 128 * 2);
    unsigned short* Wt1 = (unsigned short*)alloc((size_t)128 * 128 * 2);
    unsigned short* Wt2 = (unsigned short*)alloc((size_t)128 * 128 * 2);
    unsigned short* Wt3 = (unsigned short*)alloc((size_t)64 * 128 * 2);

    const int g_gemm = (NN + 63) / 64;      // 782
    const int f_grid = (NN + 15) / 16;      // 3125

    // bfill + es sentinel zero (tiny async memsets, graph-capturable)
    hipMemsetAsync(bfill, 0, (size_t)NB * 4, stream);
    hipMemsetAsync(es + ZOFF, 0, 16 * 4, stream);
    // weights transpose (224 blocks) || edge partition (196 blocks)
    k_pp<<<PREP_GRID + PART_GRID, 256, 0, stream>>>(
        W0, W1, W2, W3, Wt0, Wt1, Wt2, Wt3, esrc, edst, ew, bfill, ep);
    // within-bucket sort (391 blocks) || gemm0 (782 blocks)
    k_sg<<<NB + g_gemm, 256, 0, stream>>>(
        ep, bfill, es, begend, x, Wt0, s8a, NN);

    // fused: agg0(+b0,relu) -> gemm1 -> s8b (fp8)
    k_fused<128, unsigned char><<<f_grid, 256, 0, stream>>>(s8a, begend, es, b0, Wt1, s8b, NN);
    // fused: agg1(+b1,relu) -> gemm2 -> s8a (fp8)
    k_fused<128, unsigned char><<<f_grid, 256, 0, stream>>>(s8b, begend, es, b1, Wt2, s8a, NN);
    // fused: agg2(+b2,relu) -> gemm3 (64 cols) -> s16 (bf16)
    k_fused<64, unsigned short><<<f_grid, 256, 0, stream>>>(s8a, begend, es, b2, Wt3, s16, NN);
    // final: agg3 + b3, no relu, fp32 out
    k_agg64<<<f_grid, 256, 0, stream>>>(s16, begend, es, b3, (float*)d_out);
}

// Round 11
// 233.280 us; speedup vs baseline: 1.0233x; 1.0233x over previous
//
#include <hip/hip_runtime.h>

// GCN: h' = relu(A @ (h @ W) + b) x3, last layer no relu.
// Round 23 = REVERT to r21 (session best, 234.0us). r22's "tighter"
// pre-chain (memsets + prep||part + sort||gemm0) regressed to 238.7:
// the added memset dispatches cost gaps, and merging sort (critical-path
// feeder of the fused chain) with gemm0's 782 blocks delayed sort's
// completion. r21 schedule: prep -> [part || gemm0] -> sort -> fused x3
// -> agg64.
// Session ledger: 4 agg passes pinned at ~2.3-2.9 TB/s random 128B
// line-gather transaction wall (invariant to fusion/layout/depth/regs/
// decomposition across r15-r20); pre-chain schedule-optimal +-2us (r22
// probed the remaining permutation, negative). This is the floor.

constexpr int NN = 50000;          // nodes
constexpr int NE = 800000;         // edges
constexpr int NB = (NN + 127) >> 7;          // 391 buckets (dst >> 7)
constexpr int CAP = 4608;                    // padded bucket capacity
constexpr int PART_CHUNK = 4096;             // edges per partition block
constexpr int PART_GRID = (NE + PART_CHUNK - 1) / PART_CHUNK;  // 196
constexpr int ZOFF = NB * CAP;               // 16 zeroed sentinel slots

typedef __attribute__((ext_vector_type(8))) short bf16x8;
typedef __attribute__((ext_vector_type(4))) float floatx4;
typedef __attribute__((ext_vector_type(2))) float floatx2;
typedef __attribute__((ext_vector_type(4))) unsigned int uintx4;

__device__ inline unsigned short f2bf(float f) {          // RNE fp32->bf16
    unsigned u = __float_as_uint(f);
    u += 0x7fffu + ((u >> 16) & 1u);
    return (unsigned short)(u >> 16);
}
__device__ inline float bflo(unsigned v) { return __uint_as_float(v << 16); }
__device__ inline float bfhi(unsigned v) { return __uint_as_float(v & 0xffff0000u); }
__device__ inline unsigned char f2fp8(float f) {          // fp32 -> e4m3 (HW)
    return (unsigned char)(__builtin_amdgcn_cvt_pk_fp8_f32(f, f, 0, false) & 0xff);
}

// ---------------- weight transpose+convert + bfill/sentinel zero -----------

__global__ void k_prep(
        const float* __restrict__ W0, const float* __restrict__ W1,
        const float* __restrict__ W2, const float* __restrict__ W3,
        unsigned short* __restrict__ T0, unsigned short* __restrict__ T1,
        unsigned short* __restrict__ T2, unsigned short* __restrict__ T3,
        int* __restrict__ bfill, unsigned* __restrict__ es) {
    int b = blockIdx.x;              // 0..448
    if (b == 448) {
        for (int i = threadIdx.x; i < NB; i += 128) bfill[i] = 0;
        if (threadIdx.x < 16) es[ZOFF + threadIdx.x] = 0u;   // sentinel
        return;
    }
    const float* W; unsigned short* T; int N, n;
    if (b < 128)      { W = W0; T = T0; N = 128; n = b; }
    else if (b < 256) { W = W1; T = T1; N = 128; n = b - 128; }
    else if (b < 384) { W = W2; T = T2; N = 128; n = b - 256; }
    else              { W = W3; T = T3; N = 64;  n = b - 384; }
    int k = threadIdx.x;             // 0..127
    T[n * 128 + k] = f2bf(W[(size_t)k * N + n]);
}

// ---------------- merged: edge partition (blocks 0..195) -------------------
// ----------------  +  GEMM0 sup=fp8(x@W0) (blocks 196..977) ----------------

__device__ inline bf16x8 ldA_f32(const float* A, size_t off) {
    float4 u = *(const float4*)&A[off];
    float4 v = *(const float4*)&A[off + 4];
    bf16x8 r;
    r[0] = (short)f2bf(u.x); r[1] = (short)f2bf(u.y);
    r[2] = (short)f2bf(u.z); r[3] = (short)f2bf(u.w);
    r[4] = (short)f2bf(v.x); r[5] = (short)f2bf(v.y);
    r[6] = (short)f2bf(v.z); r[7] = (short)f2bf(v.w);
    return r;
}

__global__ __launch_bounds__(256) void k_pg0(
        const int* __restrict__ src, const int* __restrict__ dst,
        const float* __restrict__ w, int* __restrict__ bfill,
        int2* __restrict__ ep,
        const float* __restrict__ A,            // x [M][128] fp32
        const unsigned short* __restrict__ Wt,  // Wt0 [128][128] bf16
        unsigned char* __restrict__ C,          // sup [M][128] fp8
        int M) {
    __shared__ int hist[NB], base[NB], off[NB];          // part role
    __shared__ unsigned short sWt[128 * 136];            // gemm0 role

    const int tid = threadIdx.x;

    if (blockIdx.x < PART_GRID) {
        // ---------------- part role ----------------
        for (int b = tid; b < NB; b += 256) { hist[b] = 0; off[b] = 0; }
        __syncthreads();

        int e0 = blockIdx.x * PART_CHUNK;
        int  sreg[16]; int wreg[16]; short breg[16];
#pragma unroll
        for (int i = 0; i < 16; ++i) {
            int e = e0 + i * 256 + tid;
            if (e < NE) {
                int d = dst[e];
                int b = d >> 7;
                sreg[i] = (src[e] & 0xffff) | ((d & 127) << 16);
                wreg[i] = __float_as_int(w[e]);
                breg[i] = (short)b;
                atomicAdd(&hist[b], 1);
            } else breg[i] = -1;
        }
        __syncthreads();
        for (int b = tid; b < NB; b += 256)
            base[b] = b * CAP + atomicAdd(&bfill[b], hist[b]);
        __syncthreads();
#pragma unroll
        for (int i = 0; i < 16; ++i) {
            if (breg[i] >= 0) {
                int b = breg[i];
                int p = atomicAdd(&off[b], 1);
                ep[base[b] + p] = make_int2(sreg[i], wreg[i]);
            }
        }
        return;
    }

    // ---------------- gemm0 role ----------------
    constexpr int STR = 136;
    const int gb = blockIdx.x - PART_GRID;
#pragma unroll
    for (int i = 0; i < 8; ++i) {
        int c = i * 256 + tid;
        int row = c >> 4, col = (c & 15) * 8;
        *(uint4*)&sWt[row * STR + col] = *(const uint4*)&Wt[row * 128 + col];
    }

    const int wv = tid >> 6;
    const int ln = tid & 63;
    const int m  = ln & 15;
    const int qd = ln >> 4;

    int gr  = gb * 64 + wv * 16 + m;
    int grc = (gr < M) ? gr : (M - 1);
    bf16x8 af[4];
#pragma unroll
    for (int s = 0; s < 4; ++s)
        af[s] = ldA_f32(A, (size_t)grc * 128 + s * 32 + qd * 8);

    __syncthreads();

    floatx4 acc[8];
#pragma unroll
    for (int c = 0; c < 8; ++c) {
        acc[c] = (floatx4){0.f, 0.f, 0.f, 0.f};
#pragma unroll
        for (int s = 0; s < 4; ++s) {
            bf16x8 bf = *(const bf16x8*)&sWt[(c * 16 + m) * STR + s * 32 + qd * 8];
            acc[c] = __builtin_amdgcn_mfma_f32_16x16x32_bf16(af[s], bf, acc[c], 0, 0, 0);
        }
    }

    int row0 = gb * 64 + wv * 16 + qd * 4;
#pragma unroll
    for (int c = 0; c < 8; ++c)
#pragma unroll
        for (int r = 0; r < 4; ++r) {
            int row = row0 + r;
            if (row < M) C[(size_t)row * 128 + c * 16 + m] = f2fp8(acc[c][r]);
        }
}

// Within-bucket dst sort with per-node padding to multiple of 16.
// Emits packed 4B records: src16 | bf16(w)<<16; pad slots are 0 (w=0).
__global__ __launch_bounds__(256) void k_sort(
        const int2* __restrict__ ep, const int* __restrict__ bfill,
        unsigned* __restrict__ es, int2* __restrict__ begend) {
    __shared__ int cnt[128], base[128], fl[128];
    __shared__ int s_total;
    int b  = blockIdx.x;
    int n0 = b << 7;
    int nn = min(128, NN - n0);
    int t  = threadIdx.x;
    if (t < 128) { cnt[t] = 0; fl[t] = 0; }
    __syncthreads();
    int bbase = b * CAP;
    int beg = bbase, end = bbase + bfill[b];
    for (int e = beg + t; e < end; e += 256)
        atomicAdd(&cnt[(ep[e].x >> 16) & 127], 1);
    __syncthreads();
    int cp = (t < 128) ? ((cnt[t] + 15) & ~15) : 0;
    if (t < 128) base[t] = cp;
    __syncthreads();
    for (int off = 1; off < 128; off <<= 1) {
        int add = (t >= off && t < 128) ? base[t - off] : 0;
        __syncthreads();
        if (t < 128) base[t] += add;     // inclusive scan of padded counts
        __syncthreads();
    }
    if (t == 127) s_total = base[127];
    __syncthreads();
    int total = s_total;
    for (int i = t; i < total + 16; i += 256) es[bbase + i] = 0u;
    if (t < nn) {
        int off = base[t] - cp;
        begend[n0 + t] = make_int2(bbase + off, bbase + off + cp);
    }
    __syncthreads();
    for (int e = beg + t; e < end; e += 256) {
        int2 v = ep[e];
        int d = (v.x >> 16) & 127;
        int off = base[d] - ((cnt[d] + 15) & ~15);
        int pos = bbase + off + atomicAdd(&fl[d], 1);
        es[pos] = (unsigned)(v.x & 0xffff) |
                  ((unsigned)f2bf(__int_as_float(v.y)) << 16);
    }
}

// ---------------- Fused agg(layer i) + GEMM(layer i+1) ---------------------
// Agg phase: 16 groups x 16 lanes; group owns one node; lane l owns cols
// l*8..l*8+7 of the 128-col fp8 row (uint2 gather; 16 lanes = 128B = one
// L2 line). 8 edges/step, meta software-pipelined, sentinel clamp, all
// in-register (no shuffles). relu+bias -> bf16 tile in LDS.
// GEMM phase: 4 waves; wave wv computes col-tiles c0..c0+NT/4-1 with
// B-fragments straight from L2-hot Wt. Output row-major fp8 or bf16.

#define FMAP8(W, R)                                                             \
    { floatx2 p0 = __builtin_amdgcn_cvt_pk_f32_fp8((int)(R).x, false);          \
      floatx2 p1 = __builtin_amdgcn_cvt_pk_f32_fp8((int)(R).x, true);           \
      floatx2 p2 = __builtin_amdgcn_cvt_pk_f32_fp8((int)(R).y, false);          \
      floatx2 p3 = __builtin_amdgcn_cvt_pk_f32_fp8((int)(R).y, true);           \
      acc[0] = fmaf(W, p0.x, acc[0]); acc[1] = fmaf(W, p0.y, acc[1]);           \
      acc[2] = fmaf(W, p1.x, acc[2]); acc[3] = fmaf(W, p1.y, acc[3]);           \
      acc[4] = fmaf(W, p2.x, acc[4]); acc[5] = fmaf(W, p2.y, acc[5]);           \
      acc[6] = fmaf(W, p3.x, acc[6]); acc[7] = fmaf(W, p3.y, acc[7]); }

#define GATHF(R, MV)                                                            \
    uint2 R = *(const uint2*)&sup[(size_t)((MV) & 0xffffu) * 128 + l * 8];

template<int NOUT, typename CT>
__global__ __launch_bounds__(256) void k_fused(
        const unsigned char* __restrict__ sup,   // [NN][128] fp8
        const int2* __restrict__ begend, const unsigned* __restrict__ es,
        const float* __restrict__ bias,          // layer-i bias (relu applied)
        const unsigned short* __restrict__ Wt,   // [NOUT][128] bf16
        CT* __restrict__ C,                      // [M][NOUT] fp8 or bf16
        int M) {
    constexpr int NT  = NOUT / 16;
    constexpr int STR = 136;
    __shared__ unsigned short hT[16 * STR];

    const int tid = threadIdx.x;
    const int l   = tid & 15;                    // col slot (8 fp8 each)
    const int n0  = blockIdx.x * 16;
    const int n   = n0 + (tid >> 4);             // group's node
    const bool nv = n < NN;

    int2 be = nv ? begend[n] : make_int2(0, 0);
    const int en = be.y;
    int e = be.x;
    float acc[8] = {0.f, 0.f, 0.f, 0.f, 0.f, 0.f, 0.f, 0.f};
    bool v = e < en;
    if (__any(v)) {
        int ei = v ? e : ZOFF;
        uintx4 m0 = __builtin_nontemporal_load((const uintx4*)&es[ei]);
        uintx4 m1 = __builtin_nontemporal_load((const uintx4*)&es[ei + 4]);
        for (;;) {
            GATHF(r0, m0[0]); GATHF(r1, m0[1]); GATHF(r2, m0[2]); GATHF(r3, m0[3]);
            GATHF(r4, m1[0]); GATHF(r5, m1[1]); GATHF(r6, m1[2]); GATHF(r7, m1[3]);
            float w0 = bfhi(m0[0]), w1 = bfhi(m0[1]), w2 = bfhi(m0[2]), w3 = bfhi(m0[3]);
            float w4 = bfhi(m1[0]), w5 = bfhi(m1[1]), w6 = bfhi(m1[2]), w7 = bfhi(m1[3]);
            e += 8;
            v = e < en;
            bool more = __any(v);
            int eo = v ? e : ZOFF;               // clamp to zeroed sentinel
            uintx4 p0 = __builtin_nontemporal_load((const uintx4*)&es[eo]);
            uintx4 p1 = __builtin_nontemporal_load((const uintx4*)&es[eo + 4]);
            FMAP8(w0, r0); FMAP8(w1, r1); FMAP8(w2, r2); FMAP8(w3, r3);
            FMAP8(w4, r4); FMAP8(w5, r5); FMAP8(w6, r6); FMAP8(w7, r7);
            m0 = p0; m1 = p1;
            if (!more) break;
        }
    }
    {   // bias + relu -> bf16 LDS tile (every group writes its row slice)
        uintx4 pk;
#pragma unroll
        for (int q = 0; q < 4; ++q) {
            float a0 = fmaxf(acc[2 * q]     + bias[l * 8 + 2 * q],     0.f);
            float a1 = fmaxf(acc[2 * q + 1] + bias[l * 8 + 2 * q + 1], 0.f);
            pk[q] = (unsigned)f2bf(a0) | ((unsigned)f2bf(a1) << 16);
        }
        *(uintx4*)&hT[(tid >> 4) * STR + l * 8] = pk;
    }
    __syncthreads();

    // GEMM phase: 4 waves; wave wv owns NT/4 col-tiles.
    const int wv = tid >> 6;
    const int ln = tid & 63;
    const int m_ = ln & 15, qd = ln >> 4;
    const int c0 = wv * (NT / 4);
    bf16x8 af[4];
#pragma unroll
    for (int s = 0; s < 4; ++s)
        af[s] = *(const bf16x8*)&hT[m_ * STR + s * 32 + qd * 8];

    floatx4 acc2[NT / 4];
#pragma unroll
    for (int c = 0; c < NT / 4; ++c) {
        acc2[c] = (floatx4){0.f, 0.f, 0.f, 0.f};
#pragma unroll
        for (int s = 0; s < 4; ++s) {
            bf16x8 bf = *(const bf16x8*)&Wt[(size_t)((c0 + c) * 16 + m_) * 128 + s * 32 + qd * 8];
            acc2[c] = __builtin_amdgcn_mfma_f32_16x16x32_bf16(af[s], bf, acc2[c], 0, 0, 0);
        }
    }
    int row0 = n0 + qd * 4;
#pragma unroll
    for (int c = 0; c < NT / 4; ++c)
#pragma unroll
        for (int r = 0; r < 4; ++r) {
            int row = row0 + r;
            if (row < M) {
                if constexpr (sizeof(CT) == 1)
                    C[(size_t)row * NOUT + (c0 + c) * 16 + m_] = (CT)f2fp8(acc2[c][r]);
                else
                    C[(size_t)row * NOUT + (c0 + c) * 16 + m_] = (CT)f2bf(acc2[c][r]);
            }
        }
}

// ---------------- Final aggregate (layer 3): out fp32, no relu -------------
// Group-per-node: 16 groups x 16 lanes; lane l owns cols l*4..l*4+3 of the
// bf16 [NN][64] row (uint2 = 8B; 16 lanes = 128B = one line). 8 edges/step.

#define FMA4(W, R)                                                              \
    acc[0] = fmaf(W, bflo((R).x), acc[0]); acc[1] = fmaf(W, bfhi((R).x), acc[1]); \
    acc[2] = fmaf(W, bflo((R).y), acc[2]); acc[3] = fmaf(W, bfhi((R).y), acc[3]);

#define GATHO(R, MV)                                                            \
    uint2 R = *(const uint2*)&sup[(size_t)((MV) & 0xffffu) * 64 + l * 4];

__global__ __launch_bounds__(256) void k_agg64(
        const unsigned short* __restrict__ sup,  // [NN][64] bf16
        const int2* __restrict__ begend, const unsigned* __restrict__ es,
        const float* __restrict__ bias, float* __restrict__ out) {
    const int tid = threadIdx.x;
    const int l   = tid & 15;
    const int n   = blockIdx.x * 16 + (tid >> 4);
    const bool nv = n < NN;

    int2 be = nv ? begend[n] : make_int2(0, 0);
    const int en = be.y;
    int e = be.x;
    float acc[4] = {0.f, 0.f, 0.f, 0.f};
    bool v = e < en;
    if (__any(v)) {
        int ei = v ? e : ZOFF;
        uintx4 m0 = __builtin_nontemporal_load((const uintx4*)&es[ei]);
        uintx4 m1 = __builtin_nontemporal_load((const uintx4*)&es[ei + 4]);
        for (;;) {
            GATHO(r0, m0[0]); GATHO(r1, m0[1]); GATHO(r2, m0[2]); GATHO(r3, m0[3]);
            GATHO(r4, m1[0]); GATHO(r5, m1[1]); GATHO(r6, m1[2]); GATHO(r7, m1[3]);
            float w0 = bfhi(m0[0]), w1 = bfhi(m0[1]), w2 = bfhi(m0[2]), w3 = bfhi(m0[3]);
            float w4 = bfhi(m1[0]), w5 = bfhi(m1[1]), w6 = bfhi(m1[2]), w7 = bfhi(m1[3]);
            e += 8;
            v = e < en;
            bool more = __any(v);
            int eo = v ? e : ZOFF;               // clamp to zeroed sentinel
            uintx4 p0 = __builtin_nontemporal_load((const uintx4*)&es[eo]);
            uintx4 p1 = __builtin_nontemporal_load((const uintx4*)&es[eo + 4]);
            FMA4(w0, r0); FMA4(w1, r1); FMA4(w2, r2); FMA4(w3, r3);
            FMA4(w4, r4); FMA4(w5, r5); FMA4(w6, r6); FMA4(w7, r7);
            m0 = p0; m1 = p1;
            if (!more) break;
        }
    }
    if (nv) {
        float4 o = make_float4(acc[0] + bias[l * 4],     acc[1] + bias[l * 4 + 1],
                               acc[2] + bias[l * 4 + 2], acc[3] + bias[l * 4 + 3]);
        *(float4*)&out[(size_t)n * 64 + l * 4] = o;
    }
}

// ---------------- launch ----------------

extern "C" void kernel_launch(void* const* d_in, const int* in_sizes, int n_in,
                              void* d_out, int out_size, void* d_ws, size_t ws_size,
                              hipStream_t stream) {
    (void)in_sizes; (void)n_in; (void)out_size; (void)ws_size;

    const float* x    = (const float*)d_in[0];
    const int*   esrc = (const int*)d_in[1];
    const int*   edst = (const int*)d_in[2];
    const float* ew   = (const float*)d_in[3];
    const float* W0   = (const float*)d_in[4];
    const float* b0   = (const float*)d_in[5];
    const float* W1   = (const float*)d_in[6];
    const float* b1   = (const float*)d_in[7];
    const float* W2   = (const float*)d_in[8];
    const float* b2   = (const float*)d_in[9];
    const float* W3   = (const float*)d_in[10];
    const float* b3   = (const float*)d_in[11];

    char* p = (char*)d_ws;
    auto alloc = [&](size_t bytes) {
        char* r = p;
        p += (bytes + 511) & ~size_t(511);
        return r;
    };
    int*      bfill  = (int*)     alloc((size_t)NB * 4);
    int2*     begend = (int2*)    alloc((size_t)NN * 8);
    int2*     ep     = (int2*)    alloc((size_t)NB * CAP * 8);
    unsigned* es     = (unsigned*)alloc(((size_t)NB * CAP + 64) * 4);
    unsigned char*  s8a = (unsigned char*) alloc((size_t)NN * 128);    // [NN][128]
    unsigned char*  s8b = (unsigned char*) alloc((size_t)NN * 128);    // [NN][128]
    unsigned short* s16 = (unsigned short*)alloc((size_t)NN * 64 * 2); // [NN][64]
    unsigned short* Wt0 = (unsigned short*)alloc((size_t)128 * 128 * 2);
    unsigned short* Wt1 = (unsigned short*)alloc((size_t)128 * 128 * 2);
    unsigned short* Wt2 = (unsigned short*)alloc((size_t)128 * 128 * 2);
    unsigned short* Wt3 = (unsigned short*)alloc((size_t)64 * 128 * 2);

    const int g_gemm = (NN + 63) / 64;      // 782
    const int f_grid = (NN + 15) / 16;      // 3125

    // --- weights + bfill/sentinel zero ---
    k_prep<<<449, 128, 0, stream>>>(W0, W1, W2, W3, Wt0, Wt1, Wt2, Wt3,
                                    bfill, es);
    // merged: edge partition (196 blocks) || gemm0 (782 blocks)
    k_pg0<<<PART_GRID + g_gemm, 256, 0, stream>>>(
        esrc, edst, ew, bfill, ep, x, Wt0, s8a, NN);
    // within-bucket sort -> es/begend
    k_sort<<<NB, 256, 0, stream>>>(ep, bfill, es, begend);

    // fused: agg0(+b0,relu) -> gemm1 -> s8b (fp8)
    k_fused<128, unsigned char><<<f_grid, 256, 0, stream>>>(s8a, begend, es, b0, Wt1, s8b, NN);
    // fused: agg1(+b1,relu) -> gemm2 -> s8a (fp8)
    k_fused<128, unsigned char><<<f_grid, 256, 0, stream>>>(s8b, begend, es, b1, Wt2, s8a, NN);
    // fused: agg2(+b2,relu) -> gemm3 (64 cols) -> s16 (bf16)
    k_fused<64, unsigned short><<<f_grid, 256, 0, stream>>>(s8a, begend, es, b2, Wt3, s16, NN);
    // final: agg3 + b3, no relu, fp32 out
    k_agg64<<<f_grid, 256, 0, stream>>>(s16, begend, es, b3, (float*)d_out);
}